// Round 1
// baseline (1321.069 us; speedup 1.0000x reference)
//
#include <hip/hip_runtime.h>

#define T_DIM 512
#define B_DIM 512
#define OBS_DIM 128
#define H_DIM 128
#define A_DIM 18
#define G3 384          // 3*H
#define LDSS 136        // LDS row stride in halfs (128 + 8 pad, keeps 16B alignment, spreads banks)

typedef _Float16 v8h __attribute__((ext_vector_type(8)));
typedef _Float16 v4h __attribute__((ext_vector_type(4)));
typedef _Float16 v2h __attribute__((ext_vector_type(2)));
typedef float v4f __attribute__((ext_vector_type(4)));

__device__ __forceinline__ float sigf(float x) { return 1.0f / (1.0f + __expf(-x)); }
// tanh via 1 - 2/(1+e^{2x}): no inf/inf NaN for large |x|
__device__ __forceinline__ float tanh_fast(float x) { return 1.0f - 2.0f / (1.0f + __expf(2.0f * x)); }

// ---------------------------------------------------------------------------
// K1: gi[t,b,:] = relu(obs @ W_emb + b_emb) @ Wi + bi   (stored f16 in ws)
// block = 512 threads (8 waves). Each iteration handles 16 rows of (T*B).
// Wave w owns output cols [16w,16w+16) of emb, and col slice 16w of each gate.
// A-operand (weights^T) hoisted in registers; B-operand (rows) staged in LDS.
// ---------------------------------------------------------------------------
__global__ void k1_embed_gi(const float* __restrict__ obs,
                            const float* __restrict__ W_emb,
                            const float* __restrict__ b_emb,
                            const float* __restrict__ Wi,
                            const float* __restrict__ bi,
                            _Float16* __restrict__ gi_ws)
{
    __shared__ __align__(16) _Float16 obs_lds[16 * LDSS];
    __shared__ __align__(16) _Float16 emb_lds[16 * LDSS];
    const int tid  = threadIdx.x;
    const int wave = tid >> 6;
    const int lane = tid & 63;
    const int n16  = lane & 15;
    const int quad = lane >> 4;
    const int c16  = wave * 16 + quad * 4;

    // A-frags: A[m = out-col][k], lane: m = n16, k = kt*32 + quad*8 + j
    v8h fe[4];
    v8h fi[3][4];
#pragma unroll
    for (int kt = 0; kt < 4; ++kt) {
#pragma unroll
        for (int j = 0; j < 8; ++j) {
            const int k = kt * 32 + quad * 8 + j;
            fe[kt][j] = (_Float16)W_emb[k * H_DIM + wave * 16 + n16];
        }
    }
#pragma unroll
    for (int g = 0; g < 3; ++g) {
#pragma unroll
        for (int kt = 0; kt < 4; ++kt) {
#pragma unroll
            for (int j = 0; j < 8; ++j) {
                const int k = kt * 32 + quad * 8 + j;
                fi[g][kt][j] = (_Float16)Wi[k * G3 + g * H_DIM + wave * 16 + n16];
            }
        }
    }
    float bemb[4], bii[3][4];
#pragma unroll
    for (int r = 0; r < 4; ++r) bemb[r] = b_emb[c16 + r];
#pragma unroll
    for (int g = 0; g < 3; ++g)
#pragma unroll
        for (int r = 0; r < 4; ++r) bii[g][r] = bi[g * H_DIM + c16 + r];

    const int stage_row = tid >> 5;        // 0..15
    const int stage_k   = (tid & 31) * 4;  // 0..124

    const int iters = (T_DIM * B_DIM) / 16; // 16384
    for (int it = blockIdx.x; it < iters; it += gridDim.x) {
        const int row0 = it * 16;
        // stage 16 rows of obs -> f16 LDS (coalesced float4 loads)
        {
            const float4 v = *(const float4*)(obs + (size_t)(row0 + stage_row) * OBS_DIM + stage_k);
            v4h p; p[0] = (_Float16)v.x; p[1] = (_Float16)v.y; p[2] = (_Float16)v.z; p[3] = (_Float16)v.w;
            *(v4h*)&obs_lds[stage_row * LDSS + stage_k] = p;
        }
        __syncthreads();
        // phase A: emb tile (16 rows x 16 cols per wave)
        v8h bo[4];
#pragma unroll
        for (int kt = 0; kt < 4; ++kt)
            bo[kt] = *(const v8h*)&obs_lds[n16 * LDSS + kt * 32 + quad * 8];
        v4f ea = {0.f, 0.f, 0.f, 0.f};
#pragma unroll
        for (int kt = 0; kt < 4; ++kt)
            ea = __builtin_amdgcn_mfma_f32_16x16x32_f16(fe[kt], bo[kt], ea, 0, 0, 0);
        {
            const float e0 = fmaxf(ea[0] + bemb[0], 0.f);
            const float e1 = fmaxf(ea[1] + bemb[1], 0.f);
            const float e2 = fmaxf(ea[2] + bemb[2], 0.f);
            const float e3 = fmaxf(ea[3] + bemb[3], 0.f);
            v2h p01 = { (_Float16)e0, (_Float16)e1 };
            v2h p23 = { (_Float16)e2, (_Float16)e3 };
            *(v2h*)&emb_lds[n16 * LDSS + c16]     = p01;
            *(v2h*)&emb_lds[n16 * LDSS + c16 + 2] = p23;
        }
        __syncthreads();
        // phase B: gi tile (16 rows x 16 cols per gate per wave)
        v8h be[4];
#pragma unroll
        for (int kt = 0; kt < 4; ++kt)
            be[kt] = *(const v8h*)&emb_lds[n16 * LDSS + kt * 32 + quad * 8];
        v4f ga0 = {0.f,0.f,0.f,0.f}, ga1 = {0.f,0.f,0.f,0.f}, ga2 = {0.f,0.f,0.f,0.f};
#pragma unroll
        for (int kt = 0; kt < 4; ++kt) ga0 = __builtin_amdgcn_mfma_f32_16x16x32_f16(fi[0][kt], be[kt], ga0, 0, 0, 0);
#pragma unroll
        for (int kt = 0; kt < 4; ++kt) ga1 = __builtin_amdgcn_mfma_f32_16x16x32_f16(fi[1][kt], be[kt], ga1, 0, 0, 0);
#pragma unroll
        for (int kt = 0; kt < 4; ++kt) ga2 = __builtin_amdgcn_mfma_f32_16x16x32_f16(fi[2][kt], be[kt], ga2, 0, 0, 0);
        _Float16* gp = gi_ws + (size_t)(row0 + n16) * G3 + c16;
        {
            v2h p01, p23;
            p01[0] = (_Float16)(ga0[0] + bii[0][0]); p01[1] = (_Float16)(ga0[1] + bii[0][1]);
            p23[0] = (_Float16)(ga0[2] + bii[0][2]); p23[1] = (_Float16)(ga0[3] + bii[0][3]);
            *(v2h*)(gp) = p01; *(v2h*)(gp + 2) = p23;
            p01[0] = (_Float16)(ga1[0] + bii[1][0]); p01[1] = (_Float16)(ga1[1] + bii[1][1]);
            p23[0] = (_Float16)(ga1[2] + bii[1][2]); p23[1] = (_Float16)(ga1[3] + bii[1][3]);
            *(v2h*)(gp + H_DIM) = p01; *(v2h*)(gp + H_DIM + 2) = p23;
            p01[0] = (_Float16)(ga2[0] + bii[2][0]); p01[1] = (_Float16)(ga2[1] + bii[2][1]);
            p23[0] = (_Float16)(ga2[2] + bii[2][2]); p23[1] = (_Float16)(ga2[3] + bii[2][3]);
            *(v2h*)(gp + 2 * H_DIM) = p01; *(v2h*)(gp + 2 * H_DIM + 2) = p23;
        }
        // barriers: next iter's staging is safe (phase-A obs reads were before the
        // mid barrier); next iter's emb writes are fenced by next iter's first barrier.
    }
}

// ---------------------------------------------------------------------------
// K2: GRU recurrence + fused q-output. One block per 16 batch rows (32 blocks).
// 8 waves; wave w owns gate-col slice [16w,16w+16) of r,z,n. h state: fp32 in
// registers (C/D layout) + f16 copy in LDS for next step's B-frags.
// q[t] = ys[t] @ W_out computed by waves 0,1 from the h frags re-read at t+1.
// ---------------------------------------------------------------------------
__global__ __launch_bounds__(512) void k2_recurrence(
    const float* __restrict__ hidden,
    const unsigned char* __restrict__ dones_raw,
    const _Float16* __restrict__ gi_ws,
    const float* __restrict__ Wh,
    const float* __restrict__ bhn,
    const float* __restrict__ W_out,
    const float* __restrict__ b_out,
    float* __restrict__ out)
{
    __shared__ __align__(16) _Float16 h_lds[16 * LDSS];
    __shared__ int byte_mode;
    const int tid  = threadIdx.x;
    const int wave = tid >> 6;
    const int lane = tid & 63;
    const int n16  = lane & 15;   // batch within group
    const int quad = lane >> 4;
    const int c16  = wave * 16 + quad * 4;
    const int B0   = blockIdx.x * 16;

    if (tid == 0) byte_mode = 0;
    __syncthreads();
    {   // detect dones element width: a byte==1 at a non-4-aligned offset => 1-byte bools
        int hit = 0;
        for (int i = tid; i < 4096; i += 512)
            if ((i & 3) != 0 && dones_raw[i] == 1) hit = 1;
        if (hit) byte_mode = 1;
    }

    // Wh^T A-frags
    v8h fh[3][4];
#pragma unroll
    for (int g = 0; g < 3; ++g)
#pragma unroll
        for (int kt = 0; kt < 4; ++kt)
#pragma unroll
            for (int j = 0; j < 8; ++j) {
                const int k = kt * 32 + quad * 8 + j;
                fh[g][kt][j] = (_Float16)Wh[k * G3 + g * H_DIM + wave * 16 + n16];
            }
    // W_out^T A-frags (waves 0,1 cover q-cols 0..31; cols >=18 zero)
    v8h fo[4];
    const int qc = wave * 16 + n16;
#pragma unroll
    for (int kt = 0; kt < 4; ++kt)
#pragma unroll
        for (int j = 0; j < 8; ++j) {
            const int k = kt * 32 + quad * 8 + j;
            fo[kt][j] = (wave < 2 && qc < A_DIM) ? (_Float16)W_out[k * A_DIM + qc] : (_Float16)0.f;
        }

    float bhn_r[4], bo_r[4];
#pragma unroll
    for (int r = 0; r < 4; ++r) bhn_r[r] = bhn[c16 + r];
#pragma unroll
    for (int r = 0; r < 4; ++r) bo_r[r] = (wave < 2 && (c16 + r) < A_DIM) ? b_out[c16 + r] : 0.f;

    // init carry h (fp32 regs, lane owns batch n16, cols c16+reg) + f16 LDS copy
    float hc[4];
#pragma unroll
    for (int r = 0; r < 4; ++r) hc[r] = hidden[(size_t)(B0 + n16) * H_DIM + c16 + r];
    {
        v2h p01 = { (_Float16)hc[0], (_Float16)hc[1] };
        v2h p23 = { (_Float16)hc[2], (_Float16)hc[3] };
        *(v2h*)&h_lds[n16 * LDSS + c16]     = p01;
        *(v2h*)&h_lds[n16 * LDSS + c16 + 2] = p23;
    }
    __syncthreads();
    const bool bm = (byte_mode != 0);
    const int* dones_i32 = (const int*)dones_raw;
    const _Float16* gi_p = gi_ws + (size_t)(B0 + n16) * G3 + c16;
    float* qout = out + (size_t)B_DIM * H_DIM;

    for (int t = 0; t < T_DIM; ++t) {
        const int didx = t * B_DIM + B0 + n16;
        const bool done = bm ? (dones_raw[didx] != 0) : (dones_i32[didx] != 0);

        // B-frags: h_{t-1}[batch n16][k contiguous]
        v8h bh[4];
#pragma unroll
        for (int kt = 0; kt < 4; ++kt)
            bh[kt] = *(const v8h*)&h_lds[n16 * LDSS + kt * 32 + quad * 8];

        // q for step t-1 (pre-reset h frags = ys[t-1])
        if (wave < 2 && t > 0) {
            v4f qa = {0.f, 0.f, 0.f, 0.f};
#pragma unroll
            for (int kt = 0; kt < 4; ++kt)
                qa = __builtin_amdgcn_mfma_f32_16x16x32_f16(fo[kt], bh[kt], qa, 0, 0, 0);
            float* qp = qout + ((size_t)(t - 1) * B_DIM + B0 + n16) * A_DIM;
#pragma unroll
            for (int r = 0; r < 4; ++r)
                if (c16 + r < A_DIM) qp[c16 + r] = qa[r] + bo_r[r];
        }

        // reset (per-lane: batch = n16 for both frag and carry)
        if (done) {
#pragma unroll
            for (int kt = 0; kt < 4; ++kt)
#pragma unroll
                for (int j = 0; j < 8; ++j) bh[kt][j] = (_Float16)0.f;
        }
        float hu[4];
#pragma unroll
        for (int r = 0; r < 4; ++r) hu[r] = done ? 0.f : hc[r];

        // gh = h @ Wh (3 gates x 4 K-tiles)
        v4f ga0 = {0.f,0.f,0.f,0.f}, ga1 = {0.f,0.f,0.f,0.f}, ga2 = {0.f,0.f,0.f,0.f};
#pragma unroll
        for (int kt = 0; kt < 4; ++kt) ga0 = __builtin_amdgcn_mfma_f32_16x16x32_f16(fh[0][kt], bh[kt], ga0, 0, 0, 0);
#pragma unroll
        for (int kt = 0; kt < 4; ++kt) ga1 = __builtin_amdgcn_mfma_f32_16x16x32_f16(fh[1][kt], bh[kt], ga1, 0, 0, 0);
#pragma unroll
        for (int kt = 0; kt < 4; ++kt) ga2 = __builtin_amdgcn_mfma_f32_16x16x32_f16(fh[2][kt], bh[kt], ga2, 0, 0, 0);

        // gi loads (f16, C/D-matched addressing)
        v2h r01 = *(const v2h*)(gi_p);
        v2h r23 = *(const v2h*)(gi_p + 2);
        v2h z01 = *(const v2h*)(gi_p + H_DIM);
        v2h z23 = *(const v2h*)(gi_p + H_DIM + 2);
        v2h m01 = *(const v2h*)(gi_p + 2 * H_DIM);
        v2h m23 = *(const v2h*)(gi_p + 2 * H_DIM + 2);
        const float gir[4] = {(float)r01[0], (float)r01[1], (float)r23[0], (float)r23[1]};
        const float giz[4] = {(float)z01[0], (float)z01[1], (float)z23[0], (float)z23[1]};
        const float gin[4] = {(float)m01[0], (float)m01[1], (float)m23[0], (float)m23[1]};

        const float gaR[4] = {ga0[0], ga0[1], ga0[2], ga0[3]};
        const float gaZ[4] = {ga1[0], ga1[1], ga1[2], ga1[3]};
        const float gaN[4] = {ga2[0], ga2[1], ga2[2], ga2[3]};
#pragma unroll
        for (int r = 0; r < 4; ++r) {
            const float rr = sigf(gir[r] + gaR[r]);
            const float zz = sigf(giz[r] + gaZ[r]);
            const float nn = tanh_fast(gin[r] + rr * (gaN[r] + bhn_r[r]));
            hc[r] = (1.f - zz) * nn + zz * hu[r];
        }

        __syncthreads();   // all frag reads done before overwrite
        {
            v2h p01 = { (_Float16)hc[0], (_Float16)hc[1] };
            v2h p23 = { (_Float16)hc[2], (_Float16)hc[3] };
            *(v2h*)&h_lds[n16 * LDSS + c16]     = p01;
            *(v2h*)&h_lds[n16 * LDSS + c16 + 2] = p23;
        }
        __syncthreads();   // writes visible before next step's reads
        gi_p += (size_t)B_DIM * G3;
    }

    // final q for t = 511
    {
        v8h bh[4];
#pragma unroll
        for (int kt = 0; kt < 4; ++kt)
            bh[kt] = *(const v8h*)&h_lds[n16 * LDSS + kt * 32 + quad * 8];
        if (wave < 2) {
            v4f qa = {0.f, 0.f, 0.f, 0.f};
#pragma unroll
            for (int kt = 0; kt < 4; ++kt)
                qa = __builtin_amdgcn_mfma_f32_16x16x32_f16(fo[kt], bh[kt], qa, 0, 0, 0);
            float* qp = qout + ((size_t)(T_DIM - 1) * B_DIM + B0 + n16) * A_DIM;
#pragma unroll
            for (int r = 0; r < 4; ++r)
                if (c16 + r < A_DIM) qp[c16 + r] = qa[r] + bo_r[r];
        }
    }
    // h_final (fp32 carry, exact cols covered once per (wave,quad,reg))
#pragma unroll
    for (int r = 0; r < 4; ++r)
        out[(size_t)(B0 + n16) * H_DIM + c16 + r] = hc[r];
}

extern "C" void kernel_launch(void* const* d_in, const int* in_sizes, int n_in,
                              void* d_out, int out_size, void* d_ws, size_t ws_size,
                              hipStream_t stream) {
    const float* hidden = (const float*)d_in[0];
    const float* obs    = (const float*)d_in[1];
    const unsigned char* dones = (const unsigned char*)d_in[2];
    const float* W_emb  = (const float*)d_in[3];
    const float* b_emb  = (const float*)d_in[4];
    const float* Wi     = (const float*)d_in[5];
    const float* bi     = (const float*)d_in[6];
    const float* Wh     = (const float*)d_in[7];
    const float* bhn    = (const float*)d_in[8];
    const float* W_out  = (const float*)d_in[9];
    const float* b_out  = (const float*)d_in[10];
    float* out = (float*)d_out;
    _Float16* gi_ws = (_Float16*)d_ws;   // [T*B][384] f16 = 201 MB

    hipLaunchKernelGGL(k1_embed_gi, dim3(1024), dim3(512), 0, stream,
                       obs, W_emb, b_emb, Wi, bi, gi_ws);
    hipLaunchKernelGGL(k2_recurrence, dim3(32), dim3(512), 0, stream,
                       hidden, dones, gi_ws, Wh, bhn, W_out, b_out, out);
}

// Round 2
// 956.024 us; speedup vs baseline: 1.3818x; 1.3818x over previous
//
#include <hip/hip_runtime.h>

#define T_DIM 512
#define B_DIM 512
#define OBS_DIM 128
#define H_DIM 128
#define A_DIM 18
#define G3 384          // 3*H
#define LDSS 136        // LDS row stride in halfs (128 + 8 pad, 16B-aligned rows)

typedef _Float16 v8h __attribute__((ext_vector_type(8)));
typedef _Float16 v4h __attribute__((ext_vector_type(4)));
typedef float v4f __attribute__((ext_vector_type(4)));

// LDS-only barrier: drains lgkmcnt but leaves global (vmcnt) prefetches in
// flight across the barrier. HIP's __syncthreads would emit
// s_waitcnt vmcnt(0) lgkmcnt(0) and kill the software pipeline.
#define BAR() asm volatile("s_waitcnt lgkmcnt(0)\n\ts_barrier" ::: "memory")

__device__ __forceinline__ float sigf(float x) { return 1.0f / (1.0f + __expf(-x)); }
__device__ __forceinline__ float tanh_fast(float x) { return 1.0f - 2.0f / (1.0f + __expf(2.0f * x)); }

// ---------------------------------------------------------------------------
// K1: gi[t,b,:] = relu(obs @ W_emb + b_emb) @ Wi + bi   (stored f16 in ws)
// 512 thr (8 waves), 16 rows of (T*B) per iter. Weights^T hoisted in regs.
// obs for iter+1 prefetched into regs during iter (vmcnt stays in flight
// across the lgkm-only barriers).
// ---------------------------------------------------------------------------
__global__ __launch_bounds__(512) void k1_embed_gi(
    const float* __restrict__ obs,
    const float* __restrict__ W_emb,
    const float* __restrict__ b_emb,
    const float* __restrict__ Wi,
    const float* __restrict__ bi,
    _Float16* __restrict__ gi_ws)
{
    __shared__ __align__(16) _Float16 obs_lds[16 * LDSS];
    __shared__ __align__(16) _Float16 emb_lds[16 * LDSS];
    const int tid  = threadIdx.x;
    const int wave = tid >> 6;
    const int lane = tid & 63;
    const int n16  = lane & 15;
    const int quad = lane >> 4;
    const int c16  = wave * 16 + quad * 4;

    // A-frags: A[m = out-col][k], lane: m = n16, k = kt*32 + quad*8 + j
    v8h fe[4];
    v8h fi[3][4];
#pragma unroll
    for (int kt = 0; kt < 4; ++kt)
#pragma unroll
        for (int j = 0; j < 8; ++j) {
            const int k = kt * 32 + quad * 8 + j;
            fe[kt][j] = (_Float16)W_emb[k * H_DIM + wave * 16 + n16];
        }
#pragma unroll
    for (int g = 0; g < 3; ++g)
#pragma unroll
        for (int kt = 0; kt < 4; ++kt)
#pragma unroll
            for (int j = 0; j < 8; ++j) {
                const int k = kt * 32 + quad * 8 + j;
                fi[g][kt][j] = (_Float16)Wi[k * G3 + g * H_DIM + wave * 16 + n16];
            }
    float bemb[4], bii[3][4];
#pragma unroll
    for (int r = 0; r < 4; ++r) bemb[r] = b_emb[c16 + r];
#pragma unroll
    for (int g = 0; g < 3; ++g)
#pragma unroll
        for (int r = 0; r < 4; ++r) bii[g][r] = bi[g * H_DIM + c16 + r];

    const int stage_row = tid >> 5;        // 0..15
    const int stage_k   = (tid & 31) * 4;  // 0..124

    const int iters = (T_DIM * B_DIM) / 16; // 16384
    // stage first iteration's obs
    {
        const float4 v = *(const float4*)(obs + (size_t)(blockIdx.x * 16 + stage_row) * OBS_DIM + stage_k);
        v4h p; p[0] = (_Float16)v.x; p[1] = (_Float16)v.y; p[2] = (_Float16)v.z; p[3] = (_Float16)v.w;
        *(v4h*)&obs_lds[stage_row * LDSS + stage_k] = p;
    }
    __syncthreads();

    for (int it = blockIdx.x; it < iters; it += gridDim.x) {
        const int row0 = it * 16;
        // prefetch next iter's obs (stays in flight through both barriers)
        const int itn = (it + gridDim.x < iters) ? it + gridDim.x : it;
        const float4 nv = *(const float4*)(obs + (size_t)(itn * 16 + stage_row) * OBS_DIM + stage_k);

        // phase A: emb tile
        v8h bo[4];
#pragma unroll
        for (int kt = 0; kt < 4; ++kt)
            bo[kt] = *(const v8h*)&obs_lds[n16 * LDSS + kt * 32 + quad * 8];
        v4f ea = {0.f, 0.f, 0.f, 0.f};
#pragma unroll
        for (int kt = 0; kt < 4; ++kt)
            ea = __builtin_amdgcn_mfma_f32_16x16x32_f16(fe[kt], bo[kt], ea, 0, 0, 0);
        {
            v4h e;
#pragma unroll
            for (int r = 0; r < 4; ++r) e[r] = (_Float16)fmaxf(ea[r] + bemb[r], 0.f);
            *(v4h*)&emb_lds[n16 * LDSS + c16] = e;
        }
        BAR();
        // phase B: gi tile
        v8h be[4];
#pragma unroll
        for (int kt = 0; kt < 4; ++kt)
            be[kt] = *(const v8h*)&emb_lds[n16 * LDSS + kt * 32 + quad * 8];
        v4f ga0 = {0.f,0.f,0.f,0.f}, ga1 = {0.f,0.f,0.f,0.f}, ga2 = {0.f,0.f,0.f,0.f};
#pragma unroll
        for (int kt = 0; kt < 4; ++kt) {
            ga0 = __builtin_amdgcn_mfma_f32_16x16x32_f16(fi[0][kt], be[kt], ga0, 0, 0, 0);
            ga1 = __builtin_amdgcn_mfma_f32_16x16x32_f16(fi[1][kt], be[kt], ga1, 0, 0, 0);
            ga2 = __builtin_amdgcn_mfma_f32_16x16x32_f16(fi[2][kt], be[kt], ga2, 0, 0, 0);
        }
        _Float16* gp = gi_ws + (size_t)(row0 + n16) * G3 + c16;
        {
            v4h s0, s1, s2;
#pragma unroll
            for (int r = 0; r < 4; ++r) {
                s0[r] = (_Float16)(ga0[r] + bii[0][r]);
                s1[r] = (_Float16)(ga1[r] + bii[1][r]);
                s2[r] = (_Float16)(ga2[r] + bii[2][r]);
            }
            *(v4h*)(gp)             = s0;
            *(v4h*)(gp + H_DIM)     = s1;
            *(v4h*)(gp + 2 * H_DIM) = s2;
        }
        // stage next obs (obs_lds reads all happened before the mid barrier)
        {
            v4h p; p[0] = (_Float16)nv.x; p[1] = (_Float16)nv.y; p[2] = (_Float16)nv.z; p[3] = (_Float16)nv.w;
            *(v4h*)&obs_lds[stage_row * LDSS + stage_k] = p;
        }
        BAR();
    }
}

// ---------------------------------------------------------------------------
// K2: GRU recurrence + fused q-output. 32 blocks x 16 batch rows, 8 waves.
// h: fp32 carry in regs (C/D layout) + f16 copy in double-buffered LDS.
// dones slice staged in LDS once. gi software-pipelined one step ahead.
// One lgkm-only barrier per step.
// ---------------------------------------------------------------------------
__global__ __launch_bounds__(512) void k2_recurrence(
    const float* __restrict__ hidden,
    const unsigned char* __restrict__ dones_raw,
    const _Float16* __restrict__ gi_ws,
    const float* __restrict__ Wh,
    const float* __restrict__ bhn,
    const float* __restrict__ W_out,
    const float* __restrict__ b_out,
    float* __restrict__ out)
{
    __shared__ __align__(16) _Float16 h_lds[2][16 * LDSS];
    __shared__ __align__(16) unsigned char d_lds[T_DIM * 16];
    __shared__ int byte_mode;
    const int tid  = threadIdx.x;
    const int wave = tid >> 6;
    const int lane = tid & 63;
    const int n16  = lane & 15;   // batch within group
    const int quad = lane >> 4;
    const int c16  = wave * 16 + quad * 4;
    const int B0   = blockIdx.x * 16;

    if (tid == 0) byte_mode = 0;
    __syncthreads();
    {   // detect dones element width: byte==1 at non-4-aligned offset => 1-byte bools
        int hit = 0;
        for (int i = tid; i < 4096; i += 512)
            if ((i & 3) != 0 && dones_raw[i] == 1) hit = 1;
        if (hit) byte_mode = 1;
    }
    __syncthreads();
    const bool bm = (byte_mode != 0);

    // stage this block's dones slice into LDS: d_lds[t*16 + b] (bytes)
    {
        if (bm) {
            const int4 v = *(const int4*)(dones_raw + (size_t)tid * B_DIM + B0);
            *(int4*)&d_lds[tid * 16] = v;
        } else {
            const int* di = (const int*)dones_raw;
            const int* p = di + (size_t)tid * B_DIM + B0;
            int4 w; unsigned char* wb = (unsigned char*)&w;
#pragma unroll
            for (int j = 0; j < 16; ++j) wb[j] = (unsigned char)(p[j] != 0);
            *(int4*)&d_lds[tid * 16] = w;
        }
    }

    // Wh^T A-frags
    v8h fh[3][4];
#pragma unroll
    for (int g = 0; g < 3; ++g)
#pragma unroll
        for (int kt = 0; kt < 4; ++kt)
#pragma unroll
            for (int j = 0; j < 8; ++j) {
                const int k = kt * 32 + quad * 8 + j;
                fh[g][kt][j] = (_Float16)Wh[k * G3 + g * H_DIM + wave * 16 + n16];
            }
    // W_out^T A-frags (waves 0,1 cover q-cols 0..31; cols >=18 zero)
    v8h fo[4];
    const int qc = wave * 16 + n16;
#pragma unroll
    for (int kt = 0; kt < 4; ++kt)
#pragma unroll
        for (int j = 0; j < 8; ++j) {
            const int k = kt * 32 + quad * 8 + j;
            fo[kt][j] = (wave < 2 && qc < A_DIM) ? (_Float16)W_out[k * A_DIM + qc] : (_Float16)0.f;
        }

    float bhn_r[4], bo_r[4];
#pragma unroll
    for (int r = 0; r < 4; ++r) bhn_r[r] = bhn[c16 + r];
#pragma unroll
    for (int r = 0; r < 4; ++r) bo_r[r] = (wave < 2 && (c16 + r) < A_DIM) ? b_out[c16 + r] : 0.f;

    // init carry h + f16 LDS copy into buffer 0
    float hc[4];
#pragma unroll
    for (int r = 0; r < 4; ++r) hc[r] = hidden[(size_t)(B0 + n16) * H_DIM + c16 + r];
    {
        v4h p01 = { (_Float16)hc[0], (_Float16)hc[1], (_Float16)hc[2], (_Float16)hc[3] };
        *(v4h*)&h_lds[0][n16 * LDSS + c16] = p01;
    }
    __syncthreads();

    const _Float16* gi_p = gi_ws + (size_t)(B0 + n16) * G3 + c16;
    float* qout = out + (size_t)B_DIM * H_DIM;

    // software pipeline: gi for step t loaded during step t-1
    v4h gc0 = *(const v4h*)(gi_p);
    v4h gc1 = *(const v4h*)(gi_p + H_DIM);
    v4h gc2 = *(const v4h*)(gi_p + 2 * H_DIM);
    unsigned char dn_cur = d_lds[n16];

    int p = 0;
    for (int t = 0; t < T_DIM; ++t) {
        // issue prefetches for t+1 first (cover = rest of this step)
        const _Float16* gp1 = (t + 1 < T_DIM) ? gi_p + (size_t)B_DIM * G3 : gi_p;
        const v4h gn0 = *(const v4h*)(gp1);
        const v4h gn1 = *(const v4h*)(gp1 + H_DIM);
        const v4h gn2 = *(const v4h*)(gp1 + 2 * H_DIM);
        const int tn = (t + 1 < T_DIM) ? t + 1 : t;
        const unsigned char dn_nxt = d_lds[tn * 16 + n16];

        // B-frags: h_{t-1}
        v8h bh[4];
#pragma unroll
        for (int kt = 0; kt < 4; ++kt)
            bh[kt] = *(const v8h*)&h_lds[p][n16 * LDSS + kt * 32 + quad * 8];

        // q for step t-1 (pre-reset h frags = ys[t-1])
        if (wave < 2 && t > 0) {
            v4f qa = {0.f, 0.f, 0.f, 0.f};
#pragma unroll
            for (int kt = 0; kt < 4; ++kt)
                qa = __builtin_amdgcn_mfma_f32_16x16x32_f16(fo[kt], bh[kt], qa, 0, 0, 0);
            float* qp = qout + ((size_t)(t - 1) * B_DIM + B0 + n16) * A_DIM;
#pragma unroll
            for (int r = 0; r < 4; ++r)
                if (c16 + r < A_DIM) qp[c16 + r] = qa[r] + bo_r[r];
        }

        // gh = h @ Wh; reset handled on the (linear) outputs, not on bh,
        // so bh stays valid for the q MFMA above.
        v4f ga0 = {0.f,0.f,0.f,0.f}, ga1 = {0.f,0.f,0.f,0.f}, ga2 = {0.f,0.f,0.f,0.f};
#pragma unroll
        for (int kt = 0; kt < 4; ++kt) {
            ga0 = __builtin_amdgcn_mfma_f32_16x16x32_f16(fh[0][kt], bh[kt], ga0, 0, 0, 0);
            ga1 = __builtin_amdgcn_mfma_f32_16x16x32_f16(fh[1][kt], bh[kt], ga1, 0, 0, 0);
            ga2 = __builtin_amdgcn_mfma_f32_16x16x32_f16(fh[2][kt], bh[kt], ga2, 0, 0, 0);
        }

        const bool done = dn_cur != 0;
#pragma unroll
        for (int r = 0; r < 4; ++r) {
            const float gR = done ? 0.f : ga0[r];
            const float gZ = done ? 0.f : ga1[r];
            const float gN = done ? 0.f : ga2[r];
            const float hu = done ? 0.f : hc[r];
            const float rr = sigf((float)gc0[r] + gR);
            const float zz = sigf((float)gc1[r] + gZ);
            const float nn = tanh_fast((float)gc2[r] + rr * (gN + bhn_r[r]));
            hc[r] = (1.f - zz) * nn + zz * hu;
        }

        // write h_t to the other buffer; single lgkm-only barrier per step
        {
            v4h w = { (_Float16)hc[0], (_Float16)hc[1], (_Float16)hc[2], (_Float16)hc[3] };
            *(v4h*)&h_lds[p ^ 1][n16 * LDSS + c16] = w;
        }
        BAR();
        p ^= 1;
        gi_p = gp1;
        gc0 = gn0; gc1 = gn1; gc2 = gn2;
        dn_cur = dn_nxt;
    }

    // final q for t = 511
    {
        v8h bh[4];
#pragma unroll
        for (int kt = 0; kt < 4; ++kt)
            bh[kt] = *(const v8h*)&h_lds[p][n16 * LDSS + kt * 32 + quad * 8];
        if (wave < 2) {
            v4f qa = {0.f, 0.f, 0.f, 0.f};
#pragma unroll
            for (int kt = 0; kt < 4; ++kt)
                qa = __builtin_amdgcn_mfma_f32_16x16x32_f16(fo[kt], bh[kt], qa, 0, 0, 0);
            float* qp = qout + ((size_t)(T_DIM - 1) * B_DIM + B0 + n16) * A_DIM;
#pragma unroll
            for (int r = 0; r < 4; ++r)
                if (c16 + r < A_DIM) qp[c16 + r] = qa[r] + bo_r[r];
        }
    }
    // h_final (fp32 carry)
#pragma unroll
    for (int r = 0; r < 4; ++r)
        out[(size_t)(B0 + n16) * H_DIM + c16 + r] = hc[r];
}

extern "C" void kernel_launch(void* const* d_in, const int* in_sizes, int n_in,
                              void* d_out, int out_size, void* d_ws, size_t ws_size,
                              hipStream_t stream) {
    const float* hidden = (const float*)d_in[0];
    const float* obs    = (const float*)d_in[1];
    const unsigned char* dones = (const unsigned char*)d_in[2];
    const float* W_emb  = (const float*)d_in[3];
    const float* b_emb  = (const float*)d_in[4];
    const float* Wi     = (const float*)d_in[5];
    const float* bi     = (const float*)d_in[6];
    const float* Wh     = (const float*)d_in[7];
    const float* bhn    = (const float*)d_in[8];
    const float* W_out  = (const float*)d_in[9];
    const float* b_out  = (const float*)d_in[10];
    float* out = (float*)d_out;
    _Float16* gi_ws = (_Float16*)d_ws;   // [T*B][384] f16 = 201 MB

    hipLaunchKernelGGL(k1_embed_gi, dim3(1024), dim3(512), 0, stream,
                       obs, W_emb, b_emb, Wi, bi, gi_ws);
    hipLaunchKernelGGL(k2_recurrence, dim3(32), dim3(512), 0, stream,
                       hidden, dones, gi_ws, Wh, bhn, W_out, b_out, out);
}

// Round 3
// 868.320 us; speedup vs baseline: 1.5214x; 1.1010x over previous
//
#include <hip/hip_runtime.h>

#define T_DIM 512
#define B_DIM 512
#define OBS_DIM 128
#define H_DIM 128
#define A_DIM 18
#define G3 384
#define LDSS 136        // LDS row stride in halfs (128 + 8 pad, 16B-aligned rows)

typedef _Float16 v8h __attribute__((ext_vector_type(8)));
typedef _Float16 v4h __attribute__((ext_vector_type(4)));
typedef float v4f __attribute__((ext_vector_type(4)));

// LDS-only barrier: drains lgkmcnt but leaves vmcnt (global prefetches/stores)
// in flight across the barrier.
#define BAR() asm volatile("s_waitcnt lgkmcnt(0)\n\ts_barrier" ::: "memory")

__device__ __forceinline__ float sigf(float x) { return 1.0f / (1.0f + __expf(-x)); }
__device__ __forceinline__ float tanh_fast(float x) { return 1.0f - 2.0f / (1.0f + __expf(2.0f * x)); }

// ---------------------------------------------------------------------------
// K1: gi = relu(obs @ W_emb + b_emb) @ Wi + bi, stored f16 as:
//   gRZ[row*256 + w*32 + quad*8 + {0..3:r, 4..7:z}]  (matches K2 load slice)
//   gN [row*128 + col]
// M=32 rows/iter, 8 waves = 8 col-groups of 16 cols (per gate), 2 row-tiles.
// 256 blocks x 32 consecutive iters.
// ---------------------------------------------------------------------------
__global__ __launch_bounds__(512) void k1_embed_gi(
    const float* __restrict__ obs,
    const float* __restrict__ W_emb,
    const float* __restrict__ b_emb,
    const float* __restrict__ Wi,
    const float* __restrict__ bi,
    _Float16* __restrict__ gRZ,
    _Float16* __restrict__ gN)
{
    __shared__ __align__(16) _Float16 obs_lds[32 * LDSS];
    __shared__ __align__(16) _Float16 emb_lds[32 * LDSS];
    const int tid  = threadIdx.x;
    const int cg   = tid >> 6;     // wave = col-group
    const int lane = tid & 63;
    const int n16  = lane & 15;
    const int quad = lane >> 4;

    // A-frags: lane holds A[m=n16][k=kt*32+quad*8+j]
    v8h fe[4];
    v8h fi[3][4];
#pragma unroll
    for (int kt = 0; kt < 4; ++kt)
#pragma unroll
        for (int j = 0; j < 8; ++j) {
            const int k = kt * 32 + quad * 8 + j;
            fe[kt][j] = (_Float16)W_emb[k * H_DIM + cg * 16 + n16];
        }
#pragma unroll
    for (int g = 0; g < 3; ++g)
#pragma unroll
        for (int kt = 0; kt < 4; ++kt)
#pragma unroll
            for (int j = 0; j < 8; ++j) {
                const int k = kt * 32 + quad * 8 + j;
                fi[g][kt][j] = (_Float16)Wi[k * G3 + g * H_DIM + cg * 16 + n16];
            }
    float bemb[4], bir[4], biz[4], bin_[4];
#pragma unroll
    for (int r = 0; r < 4; ++r) {
        const int col = cg * 16 + quad * 4 + r;
        bemb[r] = b_emb[col];
        bir[r]  = bi[col];
        biz[r]  = bi[H_DIM + col];
        bin_[r] = bi[2 * H_DIM + col];
    }

    const int srow = tid >> 4;          // 0..31
    const int sk   = (tid & 15) * 8;    // 0..120
    const int base_it = blockIdx.x * 32;

    // stage iteration 0's obs
    {
        const float* op = obs + (size_t)(base_it * 32 + srow) * OBS_DIM + sk;
        const float4 a = *(const float4*)op;
        const float4 b = *(const float4*)(op + 4);
        v4h pa = { (_Float16)a.x, (_Float16)a.y, (_Float16)a.z, (_Float16)a.w };
        v4h pb = { (_Float16)b.x, (_Float16)b.y, (_Float16)b.z, (_Float16)b.w };
        *(v4h*)&obs_lds[srow * LDSS + sk]     = pa;
        *(v4h*)&obs_lds[srow * LDSS + sk + 4] = pb;
    }
    __syncthreads();

    for (int i = 0; i < 32; ++i) {
        const int row0 = (base_it + i) * 32;
        const int ni = (i + 1 < 32) ? i + 1 : i;
        const float* opn = obs + (size_t)((base_it + ni) * 32 + srow) * OBS_DIM + sk;
        const float4 na = *(const float4*)opn;
        const float4 nb = *(const float4*)(opn + 4);

        // phase A: emb tiles (2 row-tiles x 16 cols)
        v8h bo[2][4];
#pragma unroll
        for (int rt = 0; rt < 2; ++rt)
#pragma unroll
            for (int kt = 0; kt < 4; ++kt)
                bo[rt][kt] = *(const v8h*)&obs_lds[(rt * 16 + n16) * LDSS + kt * 32 + quad * 8];
        v4f ea[2] = {{0.f,0.f,0.f,0.f},{0.f,0.f,0.f,0.f}};
#pragma unroll
        for (int rt = 0; rt < 2; ++rt)
#pragma unroll
            for (int kt = 0; kt < 4; ++kt)
                ea[rt] = __builtin_amdgcn_mfma_f32_16x16x32_f16(fe[kt], bo[rt][kt], ea[rt], 0, 0, 0);
#pragma unroll
        for (int rt = 0; rt < 2; ++rt) {
            v4h e;
#pragma unroll
            for (int r = 0; r < 4; ++r) e[r] = (_Float16)fmaxf(ea[rt][r] + bemb[r], 0.f);
            *(v4h*)&emb_lds[(rt * 16 + n16) * LDSS + cg * 16 + quad * 4] = e;
        }
        BAR();
        // phase B: gi tiles (2 row-tiles x 3 gates x 16 cols)
        v8h be[2][4];
#pragma unroll
        for (int rt = 0; rt < 2; ++rt)
#pragma unroll
            for (int kt = 0; kt < 4; ++kt)
                be[rt][kt] = *(const v8h*)&emb_lds[(rt * 16 + n16) * LDSS + kt * 32 + quad * 8];
        v4f ar[2] = {{0.f,0.f,0.f,0.f},{0.f,0.f,0.f,0.f}};
        v4f az[2] = {{0.f,0.f,0.f,0.f},{0.f,0.f,0.f,0.f}};
        v4f an[2] = {{0.f,0.f,0.f,0.f},{0.f,0.f,0.f,0.f}};
#pragma unroll
        for (int rt = 0; rt < 2; ++rt)
#pragma unroll
            for (int kt = 0; kt < 4; ++kt) {
                ar[rt] = __builtin_amdgcn_mfma_f32_16x16x32_f16(fi[0][kt], be[rt][kt], ar[rt], 0, 0, 0);
                az[rt] = __builtin_amdgcn_mfma_f32_16x16x32_f16(fi[1][kt], be[rt][kt], az[rt], 0, 0, 0);
                an[rt] = __builtin_amdgcn_mfma_f32_16x16x32_f16(fi[2][kt], be[rt][kt], an[rt], 0, 0, 0);
            }
#pragma unroll
        for (int rt = 0; rt < 2; ++rt) {
            const int R = row0 + rt * 16 + n16;
            v8h rz;
#pragma unroll
            for (int r = 0; r < 4; ++r) {
                rz[r]     = (_Float16)(ar[rt][r] + bir[r]);
                rz[4 + r] = (_Float16)(az[rt][r] + biz[r]);
            }
            *(v8h*)&gRZ[(size_t)R * 256 + cg * 32 + quad * 8] = rz;
            v4h nn;
#pragma unroll
            for (int r = 0; r < 4; ++r) nn[r] = (_Float16)(an[rt][r] + bin_[r]);
            *(v4h*)&gN[(size_t)R * 128 + cg * 16 + quad * 4] = nn;
        }
        // stage next iter's obs (obs_lds reads all happened before phase-A BAR)
        {
            v4h pa = { (_Float16)na.x, (_Float16)na.y, (_Float16)na.z, (_Float16)na.w };
            v4h pb = { (_Float16)nb.x, (_Float16)nb.y, (_Float16)nb.z, (_Float16)nb.w };
            *(v4h*)&obs_lds[srow * LDSS + sk]     = pa;
            *(v4h*)&obs_lds[srow * LDSS + sk + 4] = pb;
        }
        BAR();
    }
}

// ---------------------------------------------------------------------------
// K2: GRU recurrence only. 32 blocks x 16 batch rows, 8 waves.
// - h carry fp32 in regs; f16 copy in double-buffered LDS.
// - done[t+1] applied at WRITE time (pre-masked h) -> no gate cndmasks.
// - gi prefetched 2 steps deep (2 loads/step: rz dwordx4 + n dwordx2).
// - ys[t] stored (unmasked, f16) in-place into gN row t (consumed 2 steps ago).
// - q moved to K3.
// ---------------------------------------------------------------------------
__global__ __launch_bounds__(512) void k2_recurrence(
    const float* __restrict__ hidden,
    const unsigned char* __restrict__ dones_raw,
    const _Float16* __restrict__ gRZ,
    _Float16* __restrict__ gN,
    const float* __restrict__ Wh,
    const float* __restrict__ bhn,
    float* __restrict__ out)
{
    __shared__ __align__(16) _Float16 h_lds[2][16 * LDSS];
    __shared__ __align__(16) unsigned char d_lds[T_DIM * 16];
    __shared__ int byte_mode;
    const int tid  = threadIdx.x;
    const int w    = tid >> 6;
    const int lane = tid & 63;
    const int n16  = lane & 15;   // batch within group
    const int quad = lane >> 4;
    const int c16  = w * 16 + quad * 4;
    const int B0   = blockIdx.x * 16;

    if (tid == 0) byte_mode = 0;
    __syncthreads();
    {   // detect dones element width: byte==1 at non-4-aligned offset => 1-byte bools
        int hit = 0;
        for (int i = tid; i < 4096; i += 512)
            if ((i & 3) != 0 && dones_raw[i] == 1) hit = 1;
        if (hit) byte_mode = 1;
    }
    __syncthreads();
    const bool bm = (byte_mode != 0);

    // stage this block's dones slice: d_lds[t*16 + b]
    {
        if (bm) {
            const int4 v = *(const int4*)(dones_raw + (size_t)tid * B_DIM + B0);
            *(int4*)&d_lds[tid * 16] = v;
        } else {
            const int* di = (const int*)dones_raw;
            const int* p = di + (size_t)tid * B_DIM + B0;
            int4 wv; unsigned char* wb = (unsigned char*)&wv;
#pragma unroll
            for (int j = 0; j < 16; ++j) wb[j] = (unsigned char)(p[j] != 0);
            *(int4*)&d_lds[tid * 16] = wv;
        }
    }

    // Wh^T A-frags
    v8h fh[3][4];
#pragma unroll
    for (int g = 0; g < 3; ++g)
#pragma unroll
        for (int kt = 0; kt < 4; ++kt)
#pragma unroll
            for (int j = 0; j < 8; ++j) {
                const int k = kt * 32 + quad * 8 + j;
                fh[g][kt][j] = (_Float16)Wh[k * G3 + g * H_DIM + w * 16 + n16];
            }
    float bhnr[4];
#pragma unroll
    for (int r = 0; r < 4; ++r) bhnr[r] = bhn[c16 + r];

    __syncthreads();   // d_lds visible

    // init carry, pre-masked with done[0]
    const bool d0 = d_lds[n16] != 0;
    float hu[4];
#pragma unroll
    for (int r = 0; r < 4; ++r) {
        const float hv = hidden[(size_t)(B0 + n16) * H_DIM + c16 + r];
        hu[r] = d0 ? 0.f : hv;
    }
    {
        v4h hw = { (_Float16)hu[0], (_Float16)hu[1], (_Float16)hu[2], (_Float16)hu[3] };
        *(v4h*)&h_lds[0][n16 * LDSS + c16] = hw;
    }

    const _Float16* rzp = gRZ + (size_t)(B0 + n16) * 256 + w * 32 + quad * 8;
    _Float16*       np  = gN  + (size_t)(B0 + n16) * 128 + c16;
    const size_t RZT = (size_t)B_DIM * 256;   // per-t stride in gRZ
    const size_t NT  = (size_t)B_DIM * 128;   // per-t stride in gN

    // preload t=0, t=1
    v8h gA8 = *(const v8h*)(rzp);
    v4h gA4 = *(const v4h*)(np);
    v8h gB8 = *(const v8h*)(rzp + RZT);
    v4h gB4 = *(const v4h*)(np + NT);
    __syncthreads();   // h_lds[0] visible

    int p = 0;
    for (int t = 0; t < T_DIM; ++t) {
        // prefetch t+2 (cover = ~2 steps)
        const int tp = (t + 2 < T_DIM) ? t + 2 : T_DIM - 1;
        const v8h gC8 = *(const v8h*)(rzp + (size_t)tp * RZT);
        const v4h gC4 = *(const v4h*)(np + (size_t)tp * NT);
        const unsigned char dnx = (t + 1 < T_DIM) ? d_lds[(t + 1) * 16 + n16] : (unsigned char)0;

        // B-frags: pre-masked h_{t-1}
        v8h bh[4];
#pragma unroll
        for (int kt = 0; kt < 4; ++kt)
            bh[kt] = *(const v8h*)&h_lds[p][n16 * LDSS + kt * 32 + quad * 8];

        v4f ga0 = {0.f,0.f,0.f,0.f}, ga1 = {0.f,0.f,0.f,0.f}, ga2 = {0.f,0.f,0.f,0.f};
#pragma unroll
        for (int kt = 0; kt < 4; ++kt) {
            ga0 = __builtin_amdgcn_mfma_f32_16x16x32_f16(fh[0][kt], bh[kt], ga0, 0, 0, 0);
            ga1 = __builtin_amdgcn_mfma_f32_16x16x32_f16(fh[1][kt], bh[kt], ga1, 0, 0, 0);
            ga2 = __builtin_amdgcn_mfma_f32_16x16x32_f16(fh[2][kt], bh[kt], ga2, 0, 0, 0);
        }

        float hn[4];
#pragma unroll
        for (int r = 0; r < 4; ++r) {
            const float rr = sigf((float)gA8[r] + ga0[r]);
            const float zz = sigf((float)gA8[4 + r] + ga1[r]);
            const float nn = tanh_fast((float)gA4[r] + rr * (ga2[r] + bhnr[r]));
            hn[r] = nn + zz * (hu[r] - nn);
        }

        // ys[t] store (unmasked) — overwrites gN row t (consumed at step t-2..t)
        v4h yv = { (_Float16)hn[0], (_Float16)hn[1], (_Float16)hn[2], (_Float16)hn[3] };
        *(v4h*)(np + (size_t)t * NT) = yv;

        // mask with done[t+1] at write; carry = masked value
        const bool dn = dnx != 0;
        v4h hz = { (_Float16)0.f, (_Float16)0.f, (_Float16)0.f, (_Float16)0.f };
        v4h hv = dn ? hz : yv;
#pragma unroll
        for (int r = 0; r < 4; ++r) hu[r] = dn ? 0.f : hn[r];
        *(v4h*)&h_lds[p ^ 1][n16 * LDSS + c16] = hv;
        BAR();
        p ^= 1;
        gA8 = gB8; gA4 = gB4; gB8 = gC8; gB4 = gC4;
    }

    // h_final: hu after t=511 is unmasked (dnx forced 0)
#pragma unroll
    for (int r = 0; r < 4; ++r)
        out[(size_t)(B0 + n16) * H_DIM + c16 + r] = hu[r];
}

// ---------------------------------------------------------------------------
// K3: q = ys @ W_out + b_out over all T*B rows. ys = gN (f16, [262144][128]).
// 4096 blocks x 256 thr (4 waves x 16 rows).
// ---------------------------------------------------------------------------
__global__ __launch_bounds__(256) void k3_qout(
    const _Float16* __restrict__ ys,
    const float* __restrict__ W_out,
    const float* __restrict__ b_out,
    float* __restrict__ qout)
{
    const int tid  = threadIdx.x;
    const int wv   = tid >> 6;
    const int lane = tid & 63;
    const int n16  = lane & 15;
    const int quad = lane >> 4;
    const int R0   = blockIdx.x * 64 + wv * 16;

    v8h fo[2][4];
#pragma unroll
    for (int ct = 0; ct < 2; ++ct)
#pragma unroll
        for (int kt = 0; kt < 4; ++kt)
#pragma unroll
            for (int j = 0; j < 8; ++j) {
                const int k = kt * 32 + quad * 8 + j;
                const int col = ct * 16 + n16;
                fo[ct][kt][j] = (col < A_DIM) ? (_Float16)W_out[k * A_DIM + col] : (_Float16)0.f;
            }
    float bq0[4], bq1[4];
#pragma unroll
    for (int r = 0; r < 4; ++r) {
        const int c0 = quad * 4 + r;
        const int c1 = 16 + quad * 4 + r;
        bq0[r] = b_out[c0];                    // c0 <= 15 < 18 always valid
        bq1[r] = (c1 < A_DIM) ? b_out[c1] : 0.f;
    }

    v8h by[4];
#pragma unroll
    for (int kt = 0; kt < 4; ++kt)
        by[kt] = *(const v8h*)(ys + (size_t)(R0 + n16) * 128 + kt * 32 + quad * 8);
    v4f q0 = {0.f,0.f,0.f,0.f}, q1 = {0.f,0.f,0.f,0.f};
#pragma unroll
    for (int kt = 0; kt < 4; ++kt) {
        q0 = __builtin_amdgcn_mfma_f32_16x16x32_f16(fo[0][kt], by[kt], q0, 0, 0, 0);
        q1 = __builtin_amdgcn_mfma_f32_16x16x32_f16(fo[1][kt], by[kt], q1, 0, 0, 0);
    }
    float* qp = qout + (size_t)(R0 + n16) * A_DIM;
#pragma unroll
    for (int r = 0; r < 4; ++r) qp[quad * 4 + r] = q0[r] + bq0[r];
    if (quad == 0) {
#pragma unroll
        for (int r = 0; r < 2; ++r) qp[16 + r] = q1[r] + bq1[r];
    }
}

extern "C" void kernel_launch(void* const* d_in, const int* in_sizes, int n_in,
                              void* d_out, int out_size, void* d_ws, size_t ws_size,
                              hipStream_t stream) {
    const float* hidden = (const float*)d_in[0];
    const float* obs    = (const float*)d_in[1];
    const unsigned char* dones = (const unsigned char*)d_in[2];
    const float* W_emb  = (const float*)d_in[3];
    const float* b_emb  = (const float*)d_in[4];
    const float* Wi     = (const float*)d_in[5];
    const float* bi     = (const float*)d_in[6];
    const float* Wh     = (const float*)d_in[7];
    const float* bhn    = (const float*)d_in[8];
    const float* W_out  = (const float*)d_in[9];
    const float* b_out  = (const float*)d_in[10];
    float* out = (float*)d_out;

    _Float16* gRZ = (_Float16*)d_ws;                              // [T*B][256] f16 = 134 MB
    _Float16* gN  = gRZ + (size_t)T_DIM * B_DIM * 256;            // [T*B][128] f16 =  67 MB

    hipLaunchKernelGGL(k1_embed_gi, dim3(256), dim3(512), 0, stream,
                       obs, W_emb, b_emb, Wi, bi, gRZ, gN);
    hipLaunchKernelGGL(k2_recurrence, dim3(32), dim3(512), 0, stream,
                       hidden, dones, gRZ, gN, Wh, bhn, out);
    hipLaunchKernelGGL(k3_qout, dim3(4096), dim3(256), 0, stream,
                       gN, W_out, b_out, out + (size_t)B_DIM * H_DIM);
}

// Round 5
// 751.896 us; speedup vs baseline: 1.7570x; 1.1548x over previous
//
#include <hip/hip_runtime.h>

#define T_DIM 512
#define B_DIM 512
#define OBS_DIM 128
#define H_DIM 128
#define A_DIM 18
#define G3 384
#define LDSS 136        // LDS row stride in halfs (128 + 8 pad, 16B-aligned rows)

// exp-argument scales folded into weights/biases/stored gi:
//  r,z gates: arg' = -log2e * arg   (sigmoid(x) = 1/(1+2^(arg')))
//  n gate:    arg' = 2*log2e * arg  (tanh(x) = (2^(arg')-1)/(2^(arg')+1))
#define SC_R (-1.44269504088896f)
#define SC_N (2.88539008177793f)

typedef _Float16 v8h __attribute__((ext_vector_type(8)));
typedef _Float16 v4h __attribute__((ext_vector_type(4)));
typedef float v4f __attribute__((ext_vector_type(4)));

// direct HW intrinsics (avoid glibc macro collisions; v_exp_f32 / v_rcp_f32)
#define EXP2F(x) __builtin_amdgcn_exp2f(x)
#define RCPF(x)  __builtin_amdgcn_rcpf(x)

// LDS-only barrier: drains lgkmcnt but leaves vmcnt in flight.
#define BAR() asm volatile("s_waitcnt lgkmcnt(0)\n\ts_barrier" ::: "memory")

// ---------------------------------------------------------------------------
// K1: gi = relu(obs @ W_emb + b_emb) @ Wi + bi, stored f16 PRE-SCALED:
//   gRZ[row*256 + w*32 + quad*8 + {0..3: -log2e*r, 4..7: -log2e*z}]
//   gN [row*128 + col] = 2log2e * n
// ---------------------------------------------------------------------------
__global__ __launch_bounds__(512) void k1_embed_gi(
    const float* __restrict__ obs,
    const float* __restrict__ W_emb,
    const float* __restrict__ b_emb,
    const float* __restrict__ Wi,
    const float* __restrict__ bi,
    _Float16* __restrict__ gRZ,
    _Float16* __restrict__ gN)
{
    __shared__ __align__(16) _Float16 obs_lds[32 * LDSS];
    __shared__ __align__(16) _Float16 emb_lds[32 * LDSS];
    const int tid  = threadIdx.x;
    const int cg   = tid >> 6;     // wave = col-group
    const int lane = tid & 63;
    const int n16  = lane & 15;
    const int quad = lane >> 4;

    // A-frags: lane holds A[m=n16][k=kt*32+quad*8+j]; gate scales folded in.
    v8h fe[4];
    v8h fi[3][4];
#pragma unroll
    for (int kt = 0; kt < 4; ++kt)
#pragma unroll
        for (int j = 0; j < 8; ++j) {
            const int k = kt * 32 + quad * 8 + j;
            fe[kt][j] = (_Float16)W_emb[k * H_DIM + cg * 16 + n16];
        }
#pragma unroll
    for (int g = 0; g < 3; ++g) {
        const float sc = (g == 2) ? SC_N : SC_R;
#pragma unroll
        for (int kt = 0; kt < 4; ++kt)
#pragma unroll
            for (int j = 0; j < 8; ++j) {
                const int k = kt * 32 + quad * 8 + j;
                fi[g][kt][j] = (_Float16)(Wi[k * G3 + g * H_DIM + cg * 16 + n16] * sc);
            }
    }
    float bemb[4], bir[4], biz[4], bin_[4];
#pragma unroll
    for (int r = 0; r < 4; ++r) {
        const int col = cg * 16 + quad * 4 + r;
        bemb[r] = b_emb[col];
        bir[r]  = bi[col] * SC_R;
        biz[r]  = bi[H_DIM + col] * SC_R;
        bin_[r] = bi[2 * H_DIM + col] * SC_N;
    }

    const int srow = tid >> 4;          // 0..31
    const int sk   = (tid & 15) * 8;    // 0..120
    const int base_it = blockIdx.x * 32;

    // stage iteration 0's obs
    {
        const float* op = obs + (size_t)(base_it * 32 + srow) * OBS_DIM + sk;
        const float4 a = *(const float4*)op;
        const float4 b = *(const float4*)(op + 4);
        v4h pa = { (_Float16)a.x, (_Float16)a.y, (_Float16)a.z, (_Float16)a.w };
        v4h pb = { (_Float16)b.x, (_Float16)b.y, (_Float16)b.z, (_Float16)b.w };
        *(v4h*)&obs_lds[srow * LDSS + sk]     = pa;
        *(v4h*)&obs_lds[srow * LDSS + sk + 4] = pb;
    }
    __syncthreads();

    for (int i = 0; i < 32; ++i) {
        const int row0 = (base_it + i) * 32;
        const int ni = (i + 1 < 32) ? i + 1 : i;
        const float* opn = obs + (size_t)((base_it + ni) * 32 + srow) * OBS_DIM + sk;
        const float4 na = *(const float4*)opn;
        const float4 nb = *(const float4*)(opn + 4);

        // phase A: emb tiles (2 row-tiles x 16 cols)
        v8h bo[2][4];
#pragma unroll
        for (int rt = 0; rt < 2; ++rt)
#pragma unroll
            for (int kt = 0; kt < 4; ++kt)
                bo[rt][kt] = *(const v8h*)&obs_lds[(rt * 16 + n16) * LDSS + kt * 32 + quad * 8];
        v4f ea[2] = {{0.f,0.f,0.f,0.f},{0.f,0.f,0.f,0.f}};
#pragma unroll
        for (int rt = 0; rt < 2; ++rt)
#pragma unroll
            for (int kt = 0; kt < 4; ++kt)
                ea[rt] = __builtin_amdgcn_mfma_f32_16x16x32_f16(fe[kt], bo[rt][kt], ea[rt], 0, 0, 0);
#pragma unroll
        for (int rt = 0; rt < 2; ++rt) {
            v4h e;
#pragma unroll
            for (int r = 0; r < 4; ++r) e[r] = (_Float16)fmaxf(ea[rt][r] + bemb[r], 0.f);
            *(v4h*)&emb_lds[(rt * 16 + n16) * LDSS + cg * 16 + quad * 4] = e;
        }
        BAR();
        // phase B: gi tiles (2 row-tiles x 3 gates x 16 cols)
        v8h be[2][4];
#pragma unroll
        for (int rt = 0; rt < 2; ++rt)
#pragma unroll
            for (int kt = 0; kt < 4; ++kt)
                be[rt][kt] = *(const v8h*)&emb_lds[(rt * 16 + n16) * LDSS + kt * 32 + quad * 8];
        v4f ar[2] = {{0.f,0.f,0.f,0.f},{0.f,0.f,0.f,0.f}};
        v4f az[2] = {{0.f,0.f,0.f,0.f},{0.f,0.f,0.f,0.f}};
        v4f an[2] = {{0.f,0.f,0.f,0.f},{0.f,0.f,0.f,0.f}};
#pragma unroll
        for (int rt = 0; rt < 2; ++rt)
#pragma unroll
            for (int kt = 0; kt < 4; ++kt) {
                ar[rt] = __builtin_amdgcn_mfma_f32_16x16x32_f16(fi[0][kt], be[rt][kt], ar[rt], 0, 0, 0);
                az[rt] = __builtin_amdgcn_mfma_f32_16x16x32_f16(fi[1][kt], be[rt][kt], az[rt], 0, 0, 0);
                an[rt] = __builtin_amdgcn_mfma_f32_16x16x32_f16(fi[2][kt], be[rt][kt], an[rt], 0, 0, 0);
            }
#pragma unroll
        for (int rt = 0; rt < 2; ++rt) {
            const int R = row0 + rt * 16 + n16;
            v8h rz;
#pragma unroll
            for (int r = 0; r < 4; ++r) {
                rz[r]     = (_Float16)(ar[rt][r] + bir[r]);
                rz[4 + r] = (_Float16)(az[rt][r] + biz[r]);
            }
            *(v8h*)&gRZ[(size_t)R * 256 + cg * 32 + quad * 8] = rz;
            v4h nn;
#pragma unroll
            for (int r = 0; r < 4; ++r) nn[r] = (_Float16)(an[rt][r] + bin_[r]);
            *(v4h*)&gN[(size_t)R * 128 + cg * 16 + quad * 4] = nn;
        }
        // stage next iter's obs
        {
            v4h pa = { (_Float16)na.x, (_Float16)na.y, (_Float16)na.z, (_Float16)na.w };
            v4h pb = { (_Float16)nb.x, (_Float16)nb.y, (_Float16)nb.z, (_Float16)nb.w };
            *(v4h*)&obs_lds[srow * LDSS + sk]     = pa;
            *(v4h*)&obs_lds[srow * LDSS + sk + 4] = pb;
        }
        BAR();
    }
}

// ---------------------------------------------------------------------------
// K2: GRU recurrence. 32 blocks x 16 batch rows, 8 waves.
// Fused rational gate math (3 exp2 + 2 rcp per cell, scales pre-folded).
// Unrolled by 2: even/odd gi prefetch slots + even/odd h LDS buffers.
// ---------------------------------------------------------------------------
__global__ __launch_bounds__(512) void k2_recurrence(
    const float* __restrict__ hidden,
    const unsigned char* __restrict__ dones_raw,
    const _Float16* __restrict__ gRZ,
    _Float16* __restrict__ gN,
    const float* __restrict__ Wh,
    const float* __restrict__ bhn,
    float* __restrict__ out)
{
    __shared__ __align__(16) _Float16 h_lds[2][16 * LDSS];
    __shared__ __align__(16) unsigned char d_lds[(T_DIM + 1) * 16];
    __shared__ int byte_mode;
    const int tid  = threadIdx.x;
    const int w    = tid >> 6;
    const int lane = tid & 63;
    const int n16  = lane & 15;   // batch within group
    const int quad = lane >> 4;
    const int c16  = w * 16 + quad * 4;
    const int B0   = blockIdx.x * 16;

    if (tid == 0) byte_mode = 0;
    __syncthreads();
    {   // detect dones element width: byte==1 at non-4-aligned offset => 1-byte bools
        int hit = 0;
        for (int i = tid; i < 4096; i += 512)
            if ((i & 3) != 0 && dones_raw[i] == 1) hit = 1;
        if (hit) byte_mode = 1;
    }
    __syncthreads();
    const bool bm = (byte_mode != 0);

    // stage this block's dones slice: d_lds[t*16 + b]; row T zeroed (t=511's "next")
    {
        if (bm) {
            const int4 v = *(const int4*)(dones_raw + (size_t)tid * B_DIM + B0);
            *(int4*)&d_lds[tid * 16] = v;
        } else {
            const int* di = (const int*)dones_raw;
            const int* p = di + (size_t)tid * B_DIM + B0;
            int4 wv; unsigned char* wb = (unsigned char*)&wv;
#pragma unroll
            for (int j = 0; j < 16; ++j) wb[j] = (unsigned char)(p[j] != 0);
            *(int4*)&d_lds[tid * 16] = wv;
        }
        if (tid == 0) { int4 z = {0,0,0,0}; *(int4*)&d_lds[T_DIM * 16] = z; }
    }

    // Wh^T A-frags, gate scales folded in
    v8h fh[3][4];
#pragma unroll
    for (int g = 0; g < 3; ++g) {
        const float sc = (g == 2) ? SC_N : SC_R;
#pragma unroll
        for (int kt = 0; kt < 4; ++kt)
#pragma unroll
            for (int j = 0; j < 8; ++j) {
                const int k = kt * 32 + quad * 8 + j;
                fh[g][kt][j] = (_Float16)(Wh[k * G3 + g * H_DIM + w * 16 + n16] * sc);
            }
    }
    float bhnr[4];
#pragma unroll
    for (int r = 0; r < 4; ++r) bhnr[r] = bhn[c16 + r] * SC_N;

    __syncthreads();   // d_lds visible

    // init carry, pre-masked with done[0]
    const bool d0 = d_lds[n16] != 0;
    float hu[4];
#pragma unroll
    for (int r = 0; r < 4; ++r) {
        const float hv = hidden[(size_t)(B0 + n16) * H_DIM + c16 + r];
        hu[r] = d0 ? 0.f : hv;
    }
    {
        v4h hw = { (_Float16)hu[0], (_Float16)hu[1], (_Float16)hu[2], (_Float16)hu[3] };
        *(v4h*)&h_lds[0][n16 * LDSS + c16] = hw;
    }

    const _Float16* rzp = gRZ + (size_t)(B0 + n16) * 256 + w * 32 + quad * 8;
    _Float16*       np  = gN  + (size_t)(B0 + n16) * 128 + c16;
    const size_t RZT = (size_t)B_DIM * 256;
    const size_t NT  = (size_t)B_DIM * 128;

    // even/odd prefetch slots: S0 holds even t, S1 odd t (2-step-deep pipeline)
    v8h s8_0 = *(const v8h*)(rzp);
    v4h s4_0 = *(const v4h*)(np);
    v8h s8_1 = *(const v8h*)(rzp + RZT);
    v4h s4_1 = *(const v4h*)(np + NT);
    __syncthreads();   // h_lds[0] visible

    // one step; hin/hout are compile-time after unroll
    auto STEP = [&](int t, v8h& s8, v4h& s4, const _Float16* hin, _Float16* hout)
        __attribute__((always_inline)) -> void {
        const unsigned char dnx = d_lds[(t + 1) * 16 + n16];

        v8h bh[4];
#pragma unroll
        for (int kt = 0; kt < 4; ++kt)
            bh[kt] = *(const v8h*)&hin[n16 * LDSS + kt * 32 + quad * 8];

        v4f ga0 = {0.f,0.f,0.f,0.f}, ga1 = {0.f,0.f,0.f,0.f}, ga2 = {0.f,0.f,0.f,0.f};
#pragma unroll
        for (int kt = 0; kt < 4; ++kt) {
            ga0 = __builtin_amdgcn_mfma_f32_16x16x32_f16(fh[0][kt], bh[kt], ga0, 0, 0, 0);
            ga1 = __builtin_amdgcn_mfma_f32_16x16x32_f16(fh[1][kt], bh[kt], ga1, 0, 0, 0);
            ga2 = __builtin_amdgcn_mfma_f32_16x16x32_f16(fh[2][kt], bh[kt], ga2, 0, 0, 0);
        }

        // fused gates: er=2^(sr)=e^{-xr}; en=2^(sn)=e^{2xn}; ez=2^(sz)=e^{-xz}
        // h = [ez*(en-1) + hu*(en+1)] / [(en+1)*(1+ez)]
        float hn[4];
#pragma unroll
        for (int r = 0; r < 4; ++r) {
            const float er = EXP2F((float)s8[r] + ga0[r]);
            const float rg = RCPF(1.f + er);
            const float sn = fmaf(rg, ga2[r] + bhnr[r], (float)s4[r]);
            const float en = EXP2F(sn);
            const float ez = EXP2F((float)s8[4 + r] + ga1[r]);
            const float enp = en + 1.f;
            const float num = fmaf(hu[r], enp, (en - 1.f) * ez);
            const float den = enp * (1.f + ez);
            hn[r] = num * RCPF(den);
        }

        // ys[t] (unmasked) -> gN row t
        v4h yv = { (_Float16)hn[0], (_Float16)hn[1], (_Float16)hn[2], (_Float16)hn[3] };
        *(v4h*)(np + (size_t)t * NT) = yv;

        // mask with done[t+1] at write
        const bool dn = dnx != 0;
        v4h hz = { (_Float16)0.f, (_Float16)0.f, (_Float16)0.f, (_Float16)0.f };
        v4h hv = dn ? hz : yv;
#pragma unroll
        for (int r = 0; r < 4; ++r) hu[r] = dn ? 0.f : hn[r];
        *(v4h*)&hout[n16 * LDSS + c16] = hv;

        // prefetch t+2 into this slot (in flight across BAR)
        if (t + 2 < T_DIM) {
            s8 = *(const v8h*)(rzp + (size_t)(t + 2) * RZT);
            s4 = *(const v4h*)(np + (size_t)(t + 2) * NT);
        }
        BAR();
    };

    for (int t = 0; t < T_DIM; t += 2) {
        STEP(t,     s8_0, s4_0, h_lds[0], h_lds[1]);
        STEP(t + 1, s8_1, s4_1, h_lds[1], h_lds[0]);
    }

    // h_final (hu after t=511 is unmasked: d_lds row 512 zeroed)
#pragma unroll
    for (int r = 0; r < 4; ++r)
        out[(size_t)(B0 + n16) * H_DIM + c16 + r] = hu[r];
}

// ---------------------------------------------------------------------------
// K3: q = ys @ W_out + b_out over all T*B rows. ys = gN (f16).
// 4096 blocks x 256 thr (4 waves x 16 rows).
// ---------------------------------------------------------------------------
__global__ __launch_bounds__(256) void k3_qout(
    const _Float16* __restrict__ ys,
    const float* __restrict__ W_out,
    const float* __restrict__ b_out,
    float* __restrict__ qout)
{
    const int tid  = threadIdx.x;
    const int wv   = tid >> 6;
    const int lane = tid & 63;
    const int n16  = lane & 15;
    const int quad = lane >> 4;
    const int R0   = blockIdx.x * 64 + wv * 16;

    v8h fo[2][4];
#pragma unroll
    for (int ct = 0; ct < 2; ++ct)
#pragma unroll
        for (int kt = 0; kt < 4; ++kt)
#pragma unroll
            for (int j = 0; j < 8; ++j) {
                const int k = kt * 32 + quad * 8 + j;
                const int col = ct * 16 + n16;
                fo[ct][kt][j] = (col < A_DIM) ? (_Float16)W_out[k * A_DIM + col] : (_Float16)0.f;
            }
    float bq0[4], bq1[4];
#pragma unroll
    for (int r = 0; r < 4; ++r) {
        const int c0 = quad * 4 + r;
        const int c1 = 16 + quad * 4 + r;
        bq0[r] = b_out[c0];
        bq1[r] = (c1 < A_DIM) ? b_out[c1] : 0.f;
    }

    v8h by[4];
#pragma unroll
    for (int kt = 0; kt < 4; ++kt)
        by[kt] = *(const v8h*)(ys + (size_t)(R0 + n16) * 128 + kt * 32 + quad * 8);
    v4f q0 = {0.f,0.f,0.f,0.f}, q1 = {0.f,0.f,0.f,0.f};
#pragma unroll
    for (int kt = 0; kt < 4; ++kt) {
        q0 = __builtin_amdgcn_mfma_f32_16x16x32_f16(fo[0][kt], by[kt], q0, 0, 0, 0);
        q1 = __builtin_amdgcn_mfma_f32_16x16x32_f16(fo[1][kt], by[kt], q1, 0, 0, 0);
    }
    float* qp = qout + (size_t)(R0 + n16) * A_DIM;
#pragma unroll
    for (int r = 0; r < 4; ++r) qp[quad * 4 + r] = q0[r] + bq0[r];
    if (quad == 0) {
#pragma unroll
        for (int r = 0; r < 2; ++r) qp[16 + r] = q1[r] + bq1[r];
    }
}

extern "C" void kernel_launch(void* const* d_in, const int* in_sizes, int n_in,
                              void* d_out, int out_size, void* d_ws, size_t ws_size,
                              hipStream_t stream) {
    const float* hidden = (const float*)d_in[0];
    const float* obs    = (const float*)d_in[1];
    const unsigned char* dones = (const unsigned char*)d_in[2];
    const float* W_emb  = (const float*)d_in[3];
    const float* b_emb  = (const float*)d_in[4];
    const float* Wi     = (const float*)d_in[5];
    const float* bi     = (const float*)d_in[6];
    const float* Wh     = (const float*)d_in[7];
    const float* bhn    = (const float*)d_in[8];
    const float* W_out  = (const float*)d_in[9];
    const float* b_out  = (const float*)d_in[10];
    float* out = (float*)d_out;

    _Float16* gRZ = (_Float16*)d_ws;                              // [T*B][256] f16 = 134 MB
    _Float16* gN  = gRZ + (size_t)T_DIM * B_DIM * 256;            // [T*B][128] f16 =  67 MB

    hipLaunchKernelGGL(k1_embed_gi, dim3(256), dim3(512), 0, stream,
                       obs, W_emb, b_emb, Wi, bi, gRZ, gN);
    hipLaunchKernelGGL(k2_recurrence, dim3(32), dim3(512), 0, stream,
                       hidden, dones, gRZ, gN, Wh, bhn, out);
    hipLaunchKernelGGL(k3_qout, dim3(4096), dim3(256), 0, stream,
                       gN, W_out, b_out, out + (size_t)B_DIM * H_DIM);
}